// Round 1
// baseline (564.150 us; speedup 1.0000x reference)
//
#include <hip/hip_runtime.h>
#include <hip/hip_bf16.h>

// Sizes fixed by the problem.
#define NB 32
#define LC 1024
#define LQ 256
#define DD 512
#define NEGV (-1e10f)

typedef __attribute__((ext_vector_type(4))) float f32x4;
typedef __attribute__((ext_vector_type(8))) short s16x8;   // MFMA bf16 A/B fragment (8 bf16)
typedef __attribute__((ext_vector_type(4))) unsigned short u16x4;
typedef __attribute__((ext_vector_type(8))) unsigned short u16x8;
typedef __attribute__((ext_vector_type(4))) int i32x4;

static __device__ __forceinline__ unsigned short f2bf(float f) {
  unsigned u = __float_as_uint(f);
  u += 0x7fffu + ((u >> 16) & 1u);   // round-to-nearest-even
  return (unsigned short)(u >> 16);
}

// ---------------- kernel 1: rc[b,i] = C[b,i]·wc ; rq[b,j] = Q[b,j]·wq ----------------
__global__ __launch_bounds__(256) void k_dot(const float* __restrict__ Cg, const float* __restrict__ Qg,
                                             const float* __restrict__ W0,
                                             float* __restrict__ rc, float* __restrict__ rq) {
  const int lane = threadIdx.x & 63;
  const int wid = threadIdx.x >> 6;
  const int r = blockIdx.x * 4 + wid;
  const float* src; const float* w; float* dst;
  if (r < NB * LC) { src = Cg + (size_t)r * DD; w = W0;      dst = rc + r; }
  else { int rr = r - NB * LC; src = Qg + (size_t)rr * DD; w = W0 + DD; dst = rq + rr; }
  f32x4 a0 = *(const f32x4*)(src + lane * 8);
  f32x4 a1 = *(const f32x4*)(src + lane * 8 + 4);
  f32x4 b0 = *(const f32x4*)(w + lane * 8);
  f32x4 b1 = *(const f32x4*)(w + lane * 8 + 4);
  float s = a0[0]*b0[0] + a0[1]*b0[1] + a0[2]*b0[2] + a0[3]*b0[3]
          + a1[0]*b1[0] + a1[1]*b1[1] + a1[2]*b1[2] + a1[3]*b1[3];
  #pragma unroll
  for (int o = 32; o >= 1; o >>= 1) s += __shfl_xor(s, o);
  if (lane == 0) *dst = s;
}

// ---------------- kernel 2: S[b,i,j] = rc+rq + (C*wm)·Q  (bf16 MFMA), writes S and S^T ----------------
__global__ __launch_bounds__(256) void k_score(const float* __restrict__ Cg, const float* __restrict__ Qg,
                                               const float* __restrict__ W0,
                                               const float* __restrict__ rc, const float* __restrict__ rq,
                                               float* __restrict__ S, float* __restrict__ ST) {
  __shared__ unsigned short sA[128][40];   // [row i][k] bf16, stride 40 (pad) -> ~2-way bank alias (free)
  __shared__ unsigned short sB[128][40];   // [col j][k] bf16
  const int b = blockIdx.z;
  const int i0 = blockIdx.x * 128;
  const int j0 = blockIdx.y * 128;
  const int tid = threadIdx.x, lane = tid & 63, wid = tid >> 6;
  const int wr = wid >> 1, wc = wid & 1;
  const float* wm = W0 + 2 * DD;
  const float* Ab = Cg + ((size_t)b * LC + i0) * DD;
  const float* Bb = Qg + ((size_t)b * LQ + j0) * DD;
  f32x4 acc[4][4];
  #pragma unroll
  for (int m = 0; m < 4; ++m)
    #pragma unroll
    for (int n = 0; n < 4; ++n)
      #pragma unroll
      for (int e = 0; e < 4; ++e) acc[m][n][e] = 0.f;

  const int srow = tid >> 1, skk = (tid & 1) * 16;
  const int fr = lane & 15, fs = (lane >> 4) * 8;

  for (int k = 0; k < DD; k += 32) {
    __syncthreads();
    { // stage A = C*wm
      const float* ap = Ab + (size_t)srow * DD + k + skk;
      const float* wp = wm + k + skk;
      f32x4 v0 = *(const f32x4*)(ap + 0),  v1 = *(const f32x4*)(ap + 4);
      f32x4 v2 = *(const f32x4*)(ap + 8),  v3 = *(const f32x4*)(ap + 12);
      f32x4 w0 = *(const f32x4*)(wp + 0),  w1 = *(const f32x4*)(wp + 4);
      f32x4 w2 = *(const f32x4*)(wp + 8),  w3 = *(const f32x4*)(wp + 12);
      u16x8 t0, t1;
      #pragma unroll
      for (int e = 0; e < 4; ++e) {
        t0[e]     = f2bf(v0[e] * w0[e]);
        t0[e + 4] = f2bf(v1[e] * w1[e]);
        t1[e]     = f2bf(v2[e] * w2[e]);
        t1[e + 4] = f2bf(v3[e] * w3[e]);
      }
      *(u16x8*)&sA[srow][skk]     = t0;
      *(u16x8*)&sA[srow][skk + 8] = t1;
    }
    { // stage B = Q rows (B^T of Q^T)
      const float* bp = Bb + (size_t)srow * DD + k + skk;
      f32x4 v0 = *(const f32x4*)(bp + 0),  v1 = *(const f32x4*)(bp + 4);
      f32x4 v2 = *(const f32x4*)(bp + 8),  v3 = *(const f32x4*)(bp + 12);
      u16x8 t0, t1;
      #pragma unroll
      for (int e = 0; e < 4; ++e) {
        t0[e]     = f2bf(v0[e]);
        t0[e + 4] = f2bf(v1[e]);
        t1[e]     = f2bf(v2[e]);
        t1[e + 4] = f2bf(v3[e]);
      }
      *(u16x8*)&sB[srow][skk]     = t0;
      *(u16x8*)&sB[srow][skk + 8] = t1;
    }
    __syncthreads();
    s16x8 af[4], bfv[4];
    #pragma unroll
    for (int m = 0; m < 4; ++m) af[m] = *(const s16x8*)&sA[wr * 64 + m * 16 + fr][fs];
    #pragma unroll
    for (int n = 0; n < 4; ++n) bfv[n] = *(const s16x8*)&sB[wc * 64 + n * 16 + fr][fs];
    #pragma unroll
    for (int m = 0; m < 4; ++m)
      #pragma unroll
      for (int n = 0; n < 4; ++n)
        acc[m][n] = __builtin_amdgcn_mfma_f32_16x16x32_bf16(af[m], bfv[n], acc[m][n], 0, 0, 0);
  }

  const int fq = lane >> 4;
  #pragma unroll
  for (int m = 0; m < 4; ++m) {
    const int ib = i0 + wr * 64 + m * 16 + fq * 4;   // 4 consecutive rows ib..ib+3
    const f32x4 rc4 = *(const f32x4*)&rc[b * LC + ib];
    #pragma unroll
    for (int n = 0; n < 4; ++n) {
      const int j = j0 + wc * 64 + n * 16 + fr;
      const float rqv = rq[b * LQ + j];
      f32x4 o;
      #pragma unroll
      for (int e = 0; e < 4; ++e) o[e] = acc[m][n][e] + rc4[e] + rqv;
      #pragma unroll
      for (int e = 0; e < 4; ++e) S[((size_t)b * LC + ib + e) * LQ + j] = o[e];
      *(f32x4*)&ST[((size_t)b * LQ + j) * LC + ib] = o;
    }
  }
}

// ---------------- kernel 3: row softmax (over j, q_mask) -> SR bf16 ----------------
__global__ __launch_bounds__(256) void k_rowsm(const float* __restrict__ S, const int* __restrict__ q_mask,
                                               unsigned short* __restrict__ SR) {
  const int lane = threadIdx.x & 63, wid = threadIdx.x >> 6;
  const int r = blockIdx.x * 4 + wid;          // r = b*LC + i
  const int b = r >> 10;
  f32x4 v = *(const f32x4*)(S + (size_t)r * LQ + lane * 4);
  i32x4 mk = *(const i32x4*)(q_mask + b * LQ + lane * 4);
  #pragma unroll
  for (int e = 0; e < 4; ++e) if (mk[e] == 1) v[e] = NEGV;
  float m = fmaxf(fmaxf(v[0], v[1]), fmaxf(v[2], v[3]));
  #pragma unroll
  for (int o = 32; o >= 1; o >>= 1) m = fmaxf(m, __shfl_xor(m, o));
  float e0 = __expf(v[0] - m), e1 = __expf(v[1] - m), e2 = __expf(v[2] - m), e3 = __expf(v[3] - m);
  float s = e0 + e1 + e2 + e3;
  #pragma unroll
  for (int o = 32; o >= 1; o >>= 1) s += __shfl_xor(s, o);
  const float inv = 1.0f / s;
  u16x4 ov; ov[0] = f2bf(e0 * inv); ov[1] = f2bf(e1 * inv); ov[2] = f2bf(e2 * inv); ov[3] = f2bf(e3 * inv);
  *(u16x4*)&SR[(size_t)r * LQ + lane * 4] = ov;
}

// ---------------- kernel 4: col softmax (over i, c_mask) on S^T -> SC bf16 ([b][j][i]) ----------------
__global__ __launch_bounds__(256) void k_colsm(const float* __restrict__ ST, const int* __restrict__ c_mask,
                                               unsigned short* __restrict__ SC) {
  const int lane = threadIdx.x & 63, wid = threadIdx.x >> 6;
  const int r = blockIdx.x * 4 + wid;          // r = b*LQ + j
  const int b = r >> 8;
  const float* row = ST + (size_t)r * LC;
  const int* cm = c_mask + b * LC;
  f32x4 v[4];
  #pragma unroll
  for (int it = 0; it < 4; ++it) {
    v[it] = *(const f32x4*)(row + it * 256 + lane * 4);
    i32x4 mk = *(const i32x4*)(cm + it * 256 + lane * 4);
    #pragma unroll
    for (int e = 0; e < 4; ++e) if (mk[e] == 1) v[it][e] = NEGV;
  }
  float m = -3.4e38f;
  #pragma unroll
  for (int it = 0; it < 4; ++it)
    #pragma unroll
    for (int e = 0; e < 4; ++e) m = fmaxf(m, v[it][e]);
  #pragma unroll
  for (int o = 32; o >= 1; o >>= 1) m = fmaxf(m, __shfl_xor(m, o));
  float s = 0.f;
  #pragma unroll
  for (int it = 0; it < 4; ++it)
    #pragma unroll
    for (int e = 0; e < 4; ++e) { v[it][e] = __expf(v[it][e] - m); s += v[it][e]; }
  #pragma unroll
  for (int o = 32; o >= 1; o >>= 1) s += __shfl_xor(s, o);
  const float inv = 1.0f / s;
  #pragma unroll
  for (int it = 0; it < 4; ++it) {
    u16x4 ov;
    #pragma unroll
    for (int e = 0; e < 4; ++e) ov[e] = f2bf(v[it][e] * inv);
    *(u16x4*)&SC[(size_t)r * LC + it * 256 + lane * 4] = ov;
  }
}

// ---------------- kernel 5: T[b,j,d] = sum_i SC[b,j,i] * C[b,i,d]  (M=256,N=512,K=1024) ----------------
__global__ __launch_bounds__(256) void k_tgemm(const unsigned short* __restrict__ SC, const float* __restrict__ Cg,
                                               float* __restrict__ T) {
  __shared__ unsigned short sA[128][40];   // [j][i(k)]
  __shared__ unsigned short sB[128][40];   // [d][i(k)]  (transposed-staged)
  const int b = blockIdx.z;
  const int j0 = blockIdx.x * 128;   // gridDim.x = 2
  const int n0 = blockIdx.y * 128;   // gridDim.y = 4
  const int tid = threadIdx.x, lane = tid & 63, wid = tid >> 6;
  const int wr = wid >> 1, wc = wid & 1;
  f32x4 acc[4][4];
  #pragma unroll
  for (int m = 0; m < 4; ++m)
    #pragma unroll
    for (int n = 0; n < 4; ++n)
      #pragma unroll
      for (int e = 0; e < 4; ++e) acc[m][n][e] = 0.f;
  const int srow = tid >> 1, skk = (tid & 1) * 16;
  const int bdl = tid & 127, big = (tid >> 7) * 16;
  const unsigned short* Abase = SC + ((size_t)b * LQ + j0) * LC;
  const float* Bbase = Cg + (size_t)b * LC * DD + n0;
  const int fr = lane & 15, fs = (lane >> 4) * 8;

  for (int k = 0; k < LC; k += 32) {
    __syncthreads();
    { // A: bf16 copy
      const unsigned short* ap = Abase + (size_t)srow * LC + k + skk;
      *(u16x8*)&sA[srow][skk]     = *(const u16x8*)(ap);
      *(u16x8*)&sA[srow][skk + 8] = *(const u16x8*)(ap + 8);
    }
    { // B: transposed staging from C (fp32->bf16)
      u16x8 t0, t1;
      #pragma unroll
      for (int s_ = 0; s_ < 8; ++s_) {
        t0[s_] = f2bf(Bbase[(size_t)(k + big + s_) * DD + bdl]);
        t1[s_] = f2bf(Bbase[(size_t)(k + big + 8 + s_) * DD + bdl]);
      }
      *(u16x8*)&sB[bdl][big]     = t0;
      *(u16x8*)&sB[bdl][big + 8] = t1;
    }
    __syncthreads();
    s16x8 af[4], bfv[4];
    #pragma unroll
    for (int m = 0; m < 4; ++m) af[m] = *(const s16x8*)&sA[wr * 64 + m * 16 + fr][fs];
    #pragma unroll
    for (int n = 0; n < 4; ++n) bfv[n] = *(const s16x8*)&sB[wc * 64 + n * 16 + fr][fs];
    #pragma unroll
    for (int m = 0; m < 4; ++m)
      #pragma unroll
      for (int n = 0; n < 4; ++n)
        acc[m][n] = __builtin_amdgcn_mfma_f32_16x16x32_bf16(af[m], bfv[n], acc[m][n], 0, 0, 0);
  }
  const int fq = lane >> 4;
  #pragma unroll
  for (int m = 0; m < 4; ++m)
    #pragma unroll
    for (int n = 0; n < 4; ++n) {
      const int j = j0 + wr * 64 + m * 16 + fq * 4;
      const int d = n0 + wc * 64 + n * 16 + fr;
      #pragma unroll
      for (int e = 0; e < 4; ++e) T[((size_t)b * LQ + j + e) * DD + d] = acc[m][n][e];
    }
}

// ---------------- kernel 6: A/Bt = SR @ [Q | T], fused output epilogue ----------------
__global__ __launch_bounds__(256) void k_out(const unsigned short* __restrict__ SR, const float* __restrict__ Qg,
                                             const float* __restrict__ T, const float* __restrict__ Cg,
                                             float* __restrict__ out) {
  __shared__ unsigned short sA[128][40];   // [i][j(k)]
  __shared__ unsigned short sB[128][40];   // [d][j(k)]
  const int b = blockIdx.z;
  const int i0 = blockIdx.x * 128;   // 8 tiles
  const int n0 = blockIdx.y * 128;   // 8 tiles over virtual N=1024 ([Q | T])
  const bool qpath = (n0 < 512);
  const float* Bbase = qpath ? (Qg + (size_t)b * LQ * DD + n0)
                             : (T + (size_t)b * LQ * DD + (n0 - 512));
  const unsigned short* Abase = SR + ((size_t)b * LC + i0) * LQ;
  const int tid = threadIdx.x, lane = tid & 63, wid = tid >> 6;
  const int wr = wid >> 1, wc = wid & 1;
  f32x4 acc[4][4];
  #pragma unroll
  for (int m = 0; m < 4; ++m)
    #pragma unroll
    for (int n = 0; n < 4; ++n)
      #pragma unroll
      for (int e = 0; e < 4; ++e) acc[m][n][e] = 0.f;
  const int srow = tid >> 1, skk = (tid & 1) * 16;
  const int bdl = tid & 127, big = (tid >> 7) * 16;
  const int fr = lane & 15, fs = (lane >> 4) * 8;

  for (int k = 0; k < LQ; k += 32) {
    __syncthreads();
    {
      const unsigned short* ap = Abase + (size_t)srow * LQ + k + skk;
      *(u16x8*)&sA[srow][skk]     = *(const u16x8*)(ap);
      *(u16x8*)&sA[srow][skk + 8] = *(const u16x8*)(ap + 8);
    }
    {
      u16x8 t0, t1;
      #pragma unroll
      for (int s_ = 0; s_ < 8; ++s_) {
        t0[s_] = f2bf(Bbase[(size_t)(k + big + s_) * DD + bdl]);
        t1[s_] = f2bf(Bbase[(size_t)(k + big + 8 + s_) * DD + bdl]);
      }
      *(u16x8*)&sB[bdl][big]     = t0;
      *(u16x8*)&sB[bdl][big + 8] = t1;
    }
    __syncthreads();
    s16x8 af[4], bfv[4];
    #pragma unroll
    for (int m = 0; m < 4; ++m) af[m] = *(const s16x8*)&sA[wr * 64 + m * 16 + fr][fs];
    #pragma unroll
    for (int n = 0; n < 4; ++n) bfv[n] = *(const s16x8*)&sB[wc * 64 + n * 16 + fr][fs];
    #pragma unroll
    for (int m = 0; m < 4; ++m)
      #pragma unroll
      for (int n = 0; n < 4; ++n)
        acc[m][n] = __builtin_amdgcn_mfma_f32_16x16x32_bf16(af[m], bfv[n], acc[m][n], 0, 0, 0);
  }

  const int fq = lane >> 4;
  #pragma unroll
  for (int m = 0; m < 4; ++m)
    #pragma unroll
    for (int n = 0; n < 4; ++n) {
      const int i = i0 + wr * 64 + m * 16 + fq * 4;
      const int dl = wc * 64 + n * 16 + fr;
      #pragma unroll
      for (int e = 0; e < 4; ++e) {
        const size_t ri = (size_t)b * LC + i + e;
        const size_t orow = ri * (4 * DD);
        const float a = acc[m][n][e];
        if (qpath) {
          const int d = n0 + dl;
          const float cv = Cg[ri * DD + d];
          out[orow + d] = cv;                 // segment 0: C
          out[orow + DD + d] = a;             // segment 1: A
          out[orow + 2 * DD + d] = cv * a;    // segment 2: C*A
        } else {
          const int d = n0 - 512 + dl;
          const float cv = Cg[ri * DD + d];
          out[orow + 3 * DD + d] = cv * a;    // segment 3: C*Bt
        }
      }
    }
}

extern "C" void kernel_launch(void* const* d_in, const int* in_sizes, int n_in,
                              void* d_out, int out_size, void* d_ws, size_t ws_size,
                              hipStream_t stream) {
  const float* Cg     = (const float*)d_in[0];
  const float* Qg     = (const float*)d_in[1];
  const float* W0     = (const float*)d_in[2];
  const int*   c_mask = (const int*)d_in[3];
  const int*   q_mask = (const int*)d_in[4];
  float* out = (float*)d_out;
  char* ws = (char*)d_ws;
  (void)in_sizes; (void)n_in; (void)out_size; (void)ws_size;

  // Workspace layout (bytes); total = 117,702,656 (~112.3 MB)
  float*          rc = (float*)(ws + 0);                 // 32*1024*4      = 131072
  float*          rq = (float*)(ws + 131072);            // 32*256*4       = 32768
  float*          S  = (float*)(ws + 262144);            // 32*1024*256*4  = 33554432
  float*          ST = (float*)(ws + 33816576);          // 33554432
  unsigned short* SR = (unsigned short*)(ws + 67371008); // 32*1024*256*2  = 16777216
  unsigned short* SC = (unsigned short*)(ws + 84148224); // 16777216
  float*          T  = (float*)(ws + 100925440);         // 32*256*512*4   = 16777216

  k_dot  <<<dim3((NB * LC + NB * LQ) / 4), dim3(256), 0, stream>>>(Cg, Qg, W0, rc, rq);
  k_score<<<dim3(8, 2, NB),  dim3(256), 0, stream>>>(Cg, Qg, W0, rc, rq, S, ST);
  k_rowsm<<<dim3(NB * LC / 4), dim3(256), 0, stream>>>(S, q_mask, SR);
  k_colsm<<<dim3(NB * LQ / 4), dim3(256), 0, stream>>>(ST, c_mask, SC);
  k_tgemm<<<dim3(2, 4, NB),  dim3(256), 0, stream>>>(SC, Cg, T);
  k_out  <<<dim3(8, 8, NB),  dim3(256), 0, stream>>>(SR, Qg, T, Cg, out);
}

// Round 5
// 546.335 us; speedup vs baseline: 1.0326x; 1.0326x over previous
//
#include <hip/hip_runtime.h>
#include <hip/hip_bf16.h>

// Sizes fixed by the problem.
#define NB 32
#define LC 1024
#define LQ 256
#define DD 512
#define NEGV (-1e10f)

typedef __attribute__((ext_vector_type(4))) float f32x4;
typedef __attribute__((ext_vector_type(8))) short s16x8;   // MFMA bf16 A/B fragment (8 bf16)
typedef __attribute__((ext_vector_type(4))) unsigned short u16x4;
typedef __attribute__((ext_vector_type(8))) unsigned short u16x8;
typedef __attribute__((ext_vector_type(4))) int i32x4;

static __device__ __forceinline__ unsigned short f2bf(float f) {
  unsigned u = __float_as_uint(f);
  u += 0x7fffu + ((u >> 16) & 1u);   // round-to-nearest-even
  return (unsigned short)(u >> 16);
}
static __device__ __forceinline__ float bf2f(unsigned short u) {
  return __uint_as_float(((unsigned)u) << 16);
}

// ---------------- kernel 0: zero rc/rq (ws is poisoned 0xAA) ----------------
__global__ __launch_bounds__(256) void k_zero(float* __restrict__ p) {
  p[blockIdx.x * 256 + threadIdx.x] = 0.f;   // grid 160 -> 40960 floats (rc+rq)
}

// ---------------- kernel 1: prep — transpose C->CT, Q->QT (bf16) + fused rc/rq dots ----------------
// Tiles 64x64. C: 32b x 16r x 8d = 4096 tiles ; Q: 32b x 4r x 8d = 1024 tiles. grid.x = 5120.
__global__ __launch_bounds__(256) void k_prep(const float* __restrict__ Cg, const float* __restrict__ Qg,
                                              const float* __restrict__ W0,
                                              unsigned short* __restrict__ CT, unsigned short* __restrict__ QT,
                                              float* __restrict__ rc, float* __restrict__ rq) {
  __shared__ unsigned short tt[64][72];   // [d-local][r-local], padded stride
  const int tid = threadIdx.x;
  const int t = blockIdx.x;
  const float* src; const float* w; float* racc; unsigned short* dst; int R, r0, d0;
  if (t < 4096) {
    const int b = t >> 7, rem = t & 127;
    r0 = (rem >> 3) * 64; d0 = (rem & 7) * 64;
    src = Cg + (size_t)b * LC * DD; w = W0;       racc = rc + b * LC; dst = CT + (size_t)b * DD * LC; R = LC;
  } else {
    const int t2 = t - 4096;
    const int b = t2 >> 5, rem = t2 & 31;
    r0 = (rem >> 3) * 64; d0 = (rem & 7) * 64;
    src = Qg + (size_t)b * LQ * DD; w = W0 + DD;  racc = rq + b * LQ; dst = QT + (size_t)b * DD * LQ; R = LQ;
  }
  const int cgrp = tid & 15;            // 16 threads per row, each 4 cols
  const int c = cgrp * 4;
  const f32x4 wv = *(const f32x4*)(w + d0 + c);
  #pragma unroll
  for (int it = 0; it < 4; ++it) {
    const int rr = (tid >> 4) + 16 * it;
    f32x4 v = *(const f32x4*)(src + (size_t)(r0 + rr) * DD + d0 + c);
    tt[c + 0][rr] = f2bf(v[0]); tt[c + 1][rr] = f2bf(v[1]);
    tt[c + 2][rr] = f2bf(v[2]); tt[c + 3][rr] = f2bf(v[3]);
    float part = v[0]*wv[0] + v[1]*wv[1] + v[2]*wv[2] + v[3]*wv[3];
    part += __shfl_xor(part, 1); part += __shfl_xor(part, 2);
    part += __shfl_xor(part, 4); part += __shfl_xor(part, 8);
    if (cgrp == 0) atomicAdd(racc + r0 + rr, part);
  }
  __syncthreads();
  const int cp = tid >> 2, soff = (tid & 3) * 16;   // 4 threads per output row, 16 elems each
  u16x8 o0 = *(const u16x8*)&tt[cp][soff];
  u16x8 o1 = *(const u16x8*)&tt[cp][soff + 8];
  unsigned short* op = dst + (size_t)(d0 + cp) * R + r0 + soff;
  *(u16x8*)op = o0;
  *(u16x8*)(op + 8) = o1;
}

// ---------------- kernel 2: score + fused ROW softmax ----------------
// Tile: 64 i  x  256 j (full row). 4 waves, wave w owns j in [w*64, w*64+64).
// Writes: STb bf16 [b][j][i] (raw S, for column softmax), SR bf16 [b][i][j] (row-softmax result).
__global__ __launch_bounds__(256) void k_score_sm(const float* __restrict__ Cg, const float* __restrict__ Qg,
                                                  const float* __restrict__ W0,
                                                  const float* __restrict__ rc, const float* __restrict__ rq,
                                                  const int* __restrict__ q_mask,
                                                  unsigned short* __restrict__ STb, unsigned short* __restrict__ SR) {
  __shared__ unsigned short sA[64][40];
  __shared__ unsigned short sB[256][40];
  const int b = blockIdx.y;
  const int i0 = blockIdx.x * 64;
  const int tid = threadIdx.x, lane = tid & 63, w = tid >> 6;
  const int fr = lane & 15, fq = lane >> 4, fs = fq * 8;
  const float* wm = W0 + 2 * DD;
  f32x4 acc[4][4];
  #pragma unroll
  for (int m = 0; m < 4; ++m)
    #pragma unroll
    for (int n = 0; n < 4; ++n)
      #pragma unroll
      for (int e = 0; e < 4; ++e) acc[m][n][e] = 0.f;

  const int arow = tid >> 2, acol = (tid & 3) * 8;

  for (int k = 0; k < DD; k += 32) {
    __syncthreads();
    { // A = C*wm (64 rows x 32 k)
      const float* ap = Cg + ((size_t)b * LC + i0 + arow) * DD + k + acol;
      f32x4 v0 = *(const f32x4*)ap, v1 = *(const f32x4*)(ap + 4);
      f32x4 w0 = *(const f32x4*)(wm + k + acol), w1 = *(const f32x4*)(wm + k + acol + 4);
      u16x8 t0;
      #pragma unroll
      for (int e = 0; e < 4; ++e) { t0[e] = f2bf(v0[e] * w0[e]); t0[e + 4] = f2bf(v1[e] * w1[e]); }
      *(u16x8*)&sA[arow][acol] = t0;
    }
    #pragma unroll
    for (int it = 0; it < 4; ++it) { // B = Q (256 rows x 32 k)
      const int brow = (tid >> 2) + 64 * it;
      const float* bp = Qg + ((size_t)b * LQ + brow) * DD + k + acol;
      f32x4 v0 = *(const f32x4*)bp, v1 = *(const f32x4*)(bp + 4);
      u16x8 t0;
      #pragma unroll
      for (int e = 0; e < 4; ++e) { t0[e] = f2bf(v0[e]); t0[e + 4] = f2bf(v1[e]); }
      *(u16x8*)&sB[brow][acol] = t0;
    }
    __syncthreads();
    s16x8 af[4], bfv[4];
    #pragma unroll
    for (int m = 0; m < 4; ++m) af[m] = *(const s16x8*)&sA[m * 16 + fr][fs];
    #pragma unroll
    for (int n = 0; n < 4; ++n) bfv[n] = *(const s16x8*)&sB[w * 64 + n * 16 + fr][fs];
    #pragma unroll
    for (int m = 0; m < 4; ++m)
      #pragma unroll
      for (int n = 0; n < 4; ++n)
        acc[m][n] = __builtin_amdgcn_mfma_f32_16x16x32_bf16(af[m], bfv[n], acc[m][n], 0, 0, 0);
  }

  // ---- epilogue: add rc+rq, emit raw S^T, masked row softmax, emit SR ----
  __syncthreads();
  float* redm = (float*)&sA[0][0];       // [64][4] max partials
  float* reds = redm + 256;              // [64][4] sum partials
  f32x4 rc4[4];
  #pragma unroll
  for (int m = 0; m < 4; ++m) rc4[m] = *(const f32x4*)(rc + b * LC + i0 + m * 16 + fq * 4);
  float rqv[4]; int qm[4];
  #pragma unroll
  for (int n = 0; n < 4; ++n) {
    const int j = w * 64 + n * 16 + fr;
    rqv[n] = rq[b * LQ + j];
    qm[n] = q_mask[b * LQ + j];
  }
  #pragma unroll
  for (int m = 0; m < 4; ++m)
    #pragma unroll
    for (int n = 0; n < 4; ++n) {
      f32x4 v = acc[m][n];
      #pragma unroll
      for (int e = 0; e < 4; ++e) v[e] += rc4[m][e] + rqv[n];
      u16x4 hv;
      #pragma unroll
      for (int e = 0; e < 4; ++e) hv[e] = f2bf(v[e]);
      const int j = w * 64 + n * 16 + fr;
      *(u16x4*)&STb[((size_t)b * LQ + j) * LC + i0 + m * 16 + fq * 4] = hv;   // raw S^T
      if (qm[n] == 1) {
        #pragma unroll
        for (int e = 0; e < 4; ++e) v[e] = NEGV;
      }
      acc[m][n] = v;
    }
  // per-row (i) max across n (4) and fr (16 lanes), then across 4 waves via LDS
  f32x4 mx[4];
  #pragma unroll
  for (int m = 0; m < 4; ++m) {
    mx[m] = acc[m][0];
    #pragma unroll
    for (int n = 1; n < 4; ++n)
      #pragma unroll
      for (int e = 0; e < 4; ++e) mx[m][e] = fmaxf(mx[m][e], acc[m][n][e]);
    #pragma unroll
    for (int e = 0; e < 4; ++e) {
      float x = mx[m][e];
      x = fmaxf(x, __shfl_xor(x, 1)); x = fmaxf(x, __shfl_xor(x, 2));
      x = fmaxf(x, __shfl_xor(x, 4)); x = fmaxf(x, __shfl_xor(x, 8));
      mx[m][e] = x;
    }
  }
  if (fr == 0) {
    #pragma unroll
    for (int m = 0; m < 4; ++m)
      #pragma unroll
      for (int e = 0; e < 4; ++e) redm[(m * 16 + fq * 4 + e) * 4 + w] = mx[m][e];
  }
  __syncthreads();
  f32x4 M[4];
  #pragma unroll
  for (int m = 0; m < 4; ++m)
    #pragma unroll
    for (int e = 0; e < 4; ++e) {
      f32x4 r = *(const f32x4*)&redm[(m * 16 + fq * 4 + e) * 4];
      M[m][e] = fmaxf(fmaxf(r[0], r[1]), fmaxf(r[2], r[3]));
    }
  f32x4 sm[4];
  #pragma unroll
  for (int m = 0; m < 4; ++m) {
    #pragma unroll
    for (int e = 0; e < 4; ++e) sm[m][e] = 0.f;
    #pragma unroll
    for (int n = 0; n < 4; ++n) {
      f32x4 p;
      #pragma unroll
      for (int e = 0; e < 4; ++e) { p[e] = __expf(acc[m][n][e] - M[m][e]); sm[m][e] += p[e]; }
      acc[m][n] = p;
    }
    #pragma unroll
    for (int e = 0; e < 4; ++e) {
      float x = sm[m][e];
      x += __shfl_xor(x, 1); x += __shfl_xor(x, 2);
      x += __shfl_xor(x, 4); x += __shfl_xor(x, 8);
      sm[m][e] = x;
    }
  }
  if (fr == 0) {
    #pragma unroll
    for (int m = 0; m < 4; ++m)
      #pragma unroll
      for (int e = 0; e < 4; ++e) reds[(m * 16 + fq * 4 + e) * 4 + w] = sm[m][e];
  }
  __syncthreads();
  #pragma unroll
  for (int m = 0; m < 4; ++m) {
    f32x4 inv;
    #pragma unroll
    for (int e = 0; e < 4; ++e) {
      f32x4 r = *(const f32x4*)&reds[(m * 16 + fq * 4 + e) * 4];
      inv[e] = 1.0f / (r[0] + r[1] + r[2] + r[3]);
    }
    #pragma unroll
    for (int n = 0; n < 4; ++n) {
      const int j = w * 64 + n * 16 + fr;
      #pragma unroll
      for (int e = 0; e < 4; ++e)
        SR[((size_t)b * LC + i0 + m * 16 + fq * 4 + e) * LQ + j] = f2bf(acc[m][n][e] * inv[e]);
    }
  }
}

// ---------------- kernel 3: column softmax on STb rows -> SC bf16 [b][j][i] ----------------
__global__ __launch_bounds__(256) void k_colsm(const unsigned short* __restrict__ STb, const int* __restrict__ c_mask,
                                               unsigned short* __restrict__ SC) {
  const int lane = threadIdx.x & 63, wid = threadIdx.x >> 6;
  const int r = blockIdx.x * 4 + wid;          // r = b*LQ + j
  const int b = r >> 8;
  const unsigned short* row = STb + (size_t)r * LC;
  const int* cm = c_mask + b * LC;
  float v[16];
  #pragma unroll
  for (int sgm = 0; sgm < 2; ++sgm) {
    const int base = sgm * 512 + lane * 8;
    u16x8 h = *(const u16x8*)(row + base);
    i32x4 m0 = *(const i32x4*)(cm + base);
    i32x4 m1 = *(const i32x4*)(cm + base + 4);
    #pragma unroll
    for (int e = 0; e < 4; ++e) {
      v[sgm * 8 + e]     = (m0[e] == 1) ? NEGV : bf2f(h[e]);
      v[sgm * 8 + 4 + e] = (m1[e] == 1) ? NEGV : bf2f(h[4 + e]);
    }
  }
  float m = v[0];
  #pragma unroll
  for (int e = 1; e < 16; ++e) m = fmaxf(m, v[e]);
  #pragma unroll
  for (int o = 32; o >= 1; o >>= 1) m = fmaxf(m, __shfl_xor(m, o));
  float s = 0.f;
  #pragma unroll
  for (int e = 0; e < 16; ++e) { v[e] = __expf(v[e] - m); s += v[e]; }
  #pragma unroll
  for (int o = 32; o >= 1; o >>= 1) s += __shfl_xor(s, o);
  const float inv = 1.0f / s;
  unsigned short* orow = SC + (size_t)r * LC;
  #pragma unroll
  for (int sgm = 0; sgm < 2; ++sgm) {
    u16x8 hv;
    #pragma unroll
    for (int e = 0; e < 8; ++e) hv[e] = f2bf(v[sgm * 8 + e] * inv);
    *(u16x8*)(orow + sgm * 512 + lane * 8) = hv;
  }
}

// ---------------- kernel 4: T^T[b,d,j] = sum_i SC[b,j,i] * CT[b,d,i]  (bf16 out) ----------------
__global__ __launch_bounds__(256) void k_tgemm(const unsigned short* __restrict__ SC, const unsigned short* __restrict__ CT,
                                               unsigned short* __restrict__ TT) {
  __shared__ unsigned short sA[128][40];
  __shared__ unsigned short sB[128][40];
  const int b = blockIdx.z;
  const int j0 = blockIdx.x * 128;   // gridDim.x = 2
  const int n0 = blockIdx.y * 128;   // gridDim.y = 4 (over d)
  const int tid = threadIdx.x, lane = tid & 63, wid = tid >> 6;
  const int wr = wid >> 1, wc = wid & 1;
  const int fr = lane & 15, fq = lane >> 4, fs = fq * 8;
  f32x4 acc[4][4];
  #pragma unroll
  for (int m = 0; m < 4; ++m)
    #pragma unroll
    for (int n = 0; n < 4; ++n)
      #pragma unroll
      for (int e = 0; e < 4; ++e) acc[m][n][e] = 0.f;
  const int srow = tid >> 1, scol = (tid & 1) * 16;
  const unsigned short* Ab = SC + ((size_t)b * LQ + j0) * LC;
  const unsigned short* Bb = CT + ((size_t)b * DD + n0) * LC;

  for (int k = 0; k < LC; k += 32) {
    __syncthreads();
    const unsigned short* ap = Ab + (size_t)srow * LC + k + scol;
    const unsigned short* bp = Bb + (size_t)srow * LC + k + scol;
    *(u16x8*)&sA[srow][scol]     = *(const u16x8*)ap;
    *(u16x8*)&sA[srow][scol + 8] = *(const u16x8*)(ap + 8);
    *(u16x8*)&sB[srow][scol]     = *(const u16x8*)bp;
    *(u16x8*)&sB[srow][scol + 8] = *(const u16x8*)(bp + 8);
    __syncthreads();
    s16x8 af[4], bfv[4];
    #pragma unroll
    for (int m = 0; m < 4; ++m) af[m] = *(const s16x8*)&sA[wr * 64 + m * 16 + fr][fs];
    #pragma unroll
    for (int n = 0; n < 4; ++n) bfv[n] = *(const s16x8*)&sB[wc * 64 + n * 16 + fr][fs];
    #pragma unroll
    for (int m = 0; m < 4; ++m)
      #pragma unroll
      for (int n = 0; n < 4; ++n)
        acc[m][n] = __builtin_amdgcn_mfma_f32_16x16x32_bf16(af[m], bfv[n], acc[m][n], 0, 0, 0);
  }
  #pragma unroll
  for (int m = 0; m < 4; ++m)
    #pragma unroll
    for (int n = 0; n < 4; ++n) {
      const int j = j0 + wr * 64 + m * 16 + fq * 4;
      const int d = n0 + wc * 64 + n * 16 + fr;
      u16x4 hv;
      #pragma unroll
      for (int e = 0; e < 4; ++e) hv[e] = f2bf(acc[m][n][e]);
      *(u16x4*)&TT[((size_t)b * DD + d) * LQ + j] = hv;
    }
}

// ---------------- kernel 5: A/Bt = SR @ [QT|TT]^T, fused output epilogue ----------------
__global__ __launch_bounds__(256) void k_out(const unsigned short* __restrict__ SR, const unsigned short* __restrict__ QT,
                                             const unsigned short* __restrict__ TT, const float* __restrict__ Cg,
                                             float* __restrict__ out) {
  __shared__ unsigned short sA[128][40];
  __shared__ unsigned short sB[128][40];
  const int b = blockIdx.z;
  const int i0 = blockIdx.x * 128;   // 8 tiles
  const int n0 = blockIdx.y * 128;   // 8 tiles over virtual N=1024 ([Q | T])
  const bool qpath = (n0 < 512);
  const unsigned short* Bb = qpath ? (QT + ((size_t)b * DD + n0) * LQ)
                                   : (TT + ((size_t)b * DD + n0 - 512) * LQ);
  const unsigned short* Ab = SR + ((size_t)b * LC + i0) * LQ;
  const int tid = threadIdx.x, lane = tid & 63, wid = tid >> 6;
  const int wr = wid >> 1, wc = wid & 1;
  const int fr = lane & 15, fq = lane >> 4, fs = fq * 8;
  f32x4 acc[4][4];
  #pragma unroll
  for (int m = 0; m < 4; ++m)
    #pragma unroll
    for (int n = 0; n < 4; ++n)
      #pragma unroll
      for (int e = 0; e < 4; ++e) acc[m][n][e] = 0.f;
  const int srow = tid >> 1, scol = (tid & 1) * 16;

  for (int k = 0; k < LQ; k += 32) {
    __syncthreads();
    const unsigned short* ap = Ab + (size_t)srow * LQ + k + scol;
    const unsigned short* bp = Bb + (size_t)srow * LQ + k + scol;
    *(u16x8*)&sA[srow][scol]     = *(const u16x8*)ap;
    *(u16x8*)&sA[srow][scol + 8] = *(const u16x8*)(ap + 8);
    *(u16x8*)&sB[srow][scol]     = *(const u16x8*)bp;
    *(u16x8*)&sB[srow][scol + 8] = *(const u16x8*)(bp + 8);
    __syncthreads();
    s16x8 af[4], bfv[4];
    #pragma unroll
    for (int m = 0; m < 4; ++m) af[m] = *(const s16x8*)&sA[wr * 64 + m * 16 + fr][fs];
    #pragma unroll
    for (int n = 0; n < 4; ++n) bfv[n] = *(const s16x8*)&sB[wc * 64 + n * 16 + fr][fs];
    #pragma unroll
    for (int m = 0; m < 4; ++m)
      #pragma unroll
      for (int n = 0; n < 4; ++n)
        acc[m][n] = __builtin_amdgcn_mfma_f32_16x16x32_bf16(af[m], bfv[n], acc[m][n], 0, 0, 0);
  }

  #pragma unroll
  for (int m = 0; m < 4; ++m)
    #pragma unroll
    for (int n = 0; n < 4; ++n) {
      const int i = i0 + wr * 64 + m * 16 + fq * 4;
      const int dl = wc * 64 + n * 16 + fr;
      #pragma unroll
      for (int e = 0; e < 4; ++e) {
        const size_t ri = (size_t)b * LC + i + e;
        const size_t orow = ri * (4 * DD);
        const float a = acc[m][n][e];
        if (qpath) {
          const int d = n0 + dl;
          const float cv = Cg[ri * DD + d];
          out[orow + d] = cv;                 // segment 0: C
          out[orow + DD + d] = a;             // segment 1: A
          out[orow + 2 * DD + d] = cv * a;    // segment 2: C*A
        } else {
          const int d = n0 - 512 + dl;
          const float cv = Cg[ri * DD + d];
          out[orow + 3 * DD + d] = cv * a;    // segment 3: C*Bt
        }
      }
    }
}

extern "C" void kernel_launch(void* const* d_in, const int* in_sizes, int n_in,
                              void* d_out, int out_size, void* d_ws, size_t ws_size,
                              hipStream_t stream) {
  const float* Cg     = (const float*)d_in[0];
  const float* Qg     = (const float*)d_in[1];
  const float* W0     = (const float*)d_in[2];
  const int*   c_mask = (const int*)d_in[3];
  const int*   q_mask = (const int*)d_in[4];
  float* out = (float*)d_out;
  char* ws = (char*)d_ws;
  (void)in_sizes; (void)n_in; (void)out_size; (void)ws_size;

  // Workspace layout (bytes); total = 100,827,136 (~96.2 MB)
  float*          rc  = (float*)(ws + 0);                  // 131072
  float*          rq  = (float*)(ws + 131072);             // 32768
  unsigned short* CT  = (unsigned short*)(ws + 163840);    // 33554432  bf16 [b][d][i]
  unsigned short* QT  = (unsigned short*)(ws + 33718272);  // 8388608   bf16 [b][d][j]
  unsigned short* STb = (unsigned short*)(ws + 42106880);  // 16777216  bf16 [b][j][i] raw S^T
  unsigned short* SR  = (unsigned short*)(ws + 58884096);  // 16777216  bf16 [b][i][j] row-softmax
  unsigned short* SC  = (unsigned short*)(ws + 75661312);  // 16777216  bf16 [b][j][i] col-softmax
  unsigned short* TT  = (unsigned short*)(ws + 92438528);  // 8388608   bf16 [b][d][j] T^T

  k_zero    <<<dim3(160),        dim3(256), 0, stream>>>((float*)ws);
  k_prep    <<<dim3(5120),       dim3(256), 0, stream>>>(Cg, Qg, W0, CT, QT, rc, rq);
  k_score_sm<<<dim3(16, 32),     dim3(256), 0, stream>>>(Cg, Qg, W0, rc, rq, q_mask, STb, SR);
  k_colsm   <<<dim3(2048),       dim3(256), 0, stream>>>(STb, c_mask, SC);
  k_tgemm   <<<dim3(2, 4, NB),   dim3(256), 0, stream>>>(SC, CT, TT);
  k_out     <<<dim3(8, 8, NB),   dim3(256), 0, stream>>>(SR, QT, TT, Cg, out);
}